// Round 1
// baseline (1236.686 us; speedup 1.0000x reference)
//
#include <hip/hip_runtime.h>

#define N_NODES 131072
#define E_EDGES 524288
#define NGRAPH  16
#define NPG     8192
#define DIM     128
#define KSEL    4096

// ---------------- CSR build ----------------
__global__ void count_deg_kernel(const int* __restrict__ ei, int* __restrict__ deg) {
    int e = blockIdx.x * 256 + threadIdx.x;
    atomicAdd(&deg[ei[E_EDGES + e]], 1);
}

__global__ __launch_bounds__(1024) void scan_kernel(const int* __restrict__ deg,
                                                    int* __restrict__ rowptr,
                                                    int* __restrict__ cursor,
                                                    float* __restrict__ dis) {
    __shared__ int ssum[1024];
    int t = threadIdx.x;
    const int CH = N_NODES / 1024;  // 128
    int base = t * CH;
    int s = 0;
    for (int i = 0; i < CH; ++i) s += deg[base + i];
    ssum[t] = s;
    __syncthreads();
    for (int off = 1; off < 1024; off <<= 1) {
        int v = (t >= off) ? ssum[t - off] : 0;
        __syncthreads();
        ssum[t] += v;
        __syncthreads();
    }
    int running = ssum[t] - s;  // exclusive prefix
    for (int i = 0; i < CH; ++i) {
        int idx = base + i;
        int dg = deg[idx];
        rowptr[idx] = running;
        cursor[idx] = running;
        dis[idx] = rsqrtf((float)dg + 1.0f);
        running += dg;
    }
    if (t == 1023) rowptr[N_NODES] = running;
}

__global__ void fill_csr_kernel(const int* __restrict__ ei, int* __restrict__ cursor,
                                const float* __restrict__ dis, int* __restrict__ csr_src,
                                float* __restrict__ csr_coef) {
    int e = blockIdx.x * 256 + threadIdx.x;
    int s = ei[e];
    int d = ei[E_EDGES + e];
    int p = atomicAdd(&cursor[d], 1);
    csr_src[p] = s;
    csr_coef[p] = dis[s] * dis[d];
}

// ---------------- node embedding: h = x @ node_w + node_b ----------------
__global__ __launch_bounds__(256) void embed_kernel(const float* __restrict__ x,
                                                    const float* __restrict__ nw,
                                                    const float* __restrict__ nb,
                                                    float* __restrict__ h) {
    __shared__ float Wl[16 * DIM];
    int t = threadIdx.x;
    for (int i = t * 4; i < 16 * DIM; i += 1024)
        *(float4*)&Wl[i] = *(const float4*)&nw[i];
    __syncthreads();
    int d = t & 127, sub = t >> 7;
    float bias = nb[d];
    int base = blockIdx.x * 32;
    for (int k = 0; k < 16; ++k) {
        int n = base + k * 2 + sub;
        const float* xr = &x[n * 16];
        float acc = bias;
#pragma unroll
        for (int f = 0; f < 16; ++f) acc += xr[f] * Wl[f * DIM + d];
        h[n * DIM + d] = acc;
    }
}

// ---------------- sparse propagate: m = sum coef*h[src] + dis^2 * h ----------------
__global__ __launch_bounds__(256) void agg_kernel(const float* __restrict__ h,
                                                  const int* __restrict__ rowptr,
                                                  const int* __restrict__ csr_src,
                                                  const float* __restrict__ csr_coef,
                                                  const float* __restrict__ dis,
                                                  float* __restrict__ m) {
    int t = threadIdx.x;
    int d = t & 127;
    int sub = t >> 7;
    for (int np = blockIdx.x; np < N_NODES / 2; np += 8192) {
        int n = np * 2 + sub;
        float dn = dis[n];
        float acc = dn * dn * h[n * DIM + d];
        int e0 = rowptr[n], e1 = rowptr[n + 1];
        for (int e = e0; e < e1; ++e) {
            acc += csr_coef[e] * h[csr_src[e] * DIM + d];
        }
        m[n * DIM + d] = acc;
    }
}

// ---------------- dense: h = leaky(BN(m @ W + cb)) fused ----------------
__global__ __launch_bounds__(256) void gemm_bn_kernel(const float* __restrict__ m,
                                                      const float* __restrict__ W,
                                                      const float* __restrict__ cb,
                                                      const float* __restrict__ bg,
                                                      const float* __restrict__ bb,
                                                      const float* __restrict__ bm,
                                                      const float* __restrict__ bv,
                                                      float* __restrict__ h) {
    __shared__ float Wl[DIM * DIM];   // 64 KB
    __shared__ float Ml[32 * DIM];    // 16 KB
    int t = threadIdx.x;
    for (int i = t * 4; i < DIM * DIM; i += 1024)
        *(float4*)&Wl[i] = *(const float4*)&W[i];
    int cg = t & 31;   // column group (4 cols)
    int ns = t >> 5;   // node strip (4 nodes), 0..7
    float A[4], C[4];
#pragma unroll
    for (int c = 0; c < 4; ++c) {
        int d = cg * 4 + c;
        float inv = rsqrtf(bv[d] + 1e-5f);
        float a = bg[d] * inv;
        A[c] = a;
        C[c] = (cb[d] - bm[d]) * a + bb[d];
    }
    __syncthreads();
    for (int tile = 0; tile < 4; ++tile) {
        int base = (blockIdx.x * 4 + tile) * 32;
        __syncthreads();
        for (int i = t * 4; i < 32 * DIM; i += 1024)
            *(float4*)&Ml[i] = *(const float4*)&m[base * DIM + i];
        __syncthreads();
        float acc[4][4] = {{0.f}};
        for (int k = 0; k < DIM; k += 4) {
            float4 a0 = *(float4*)&Ml[(ns * 4 + 0) * DIM + k];
            float4 a1 = *(float4*)&Ml[(ns * 4 + 1) * DIM + k];
            float4 a2 = *(float4*)&Ml[(ns * 4 + 2) * DIM + k];
            float4 a3 = *(float4*)&Ml[(ns * 4 + 3) * DIM + k];
            float4 b0 = *(float4*)&Wl[(k + 0) * DIM + cg * 4];
            float4 b1 = *(float4*)&Wl[(k + 1) * DIM + cg * 4];
            float4 b2 = *(float4*)&Wl[(k + 2) * DIM + cg * 4];
            float4 b3 = *(float4*)&Wl[(k + 3) * DIM + cg * 4];
            float av[4][4] = {{a0.x, a0.y, a0.z, a0.w},
                              {a1.x, a1.y, a1.z, a1.w},
                              {a2.x, a2.y, a2.z, a2.w},
                              {a3.x, a3.y, a3.z, a3.w}};
            float bvv[4][4] = {{b0.x, b0.y, b0.z, b0.w},
                               {b1.x, b1.y, b1.z, b1.w},
                               {b2.x, b2.y, b2.z, b2.w},
                               {b3.x, b3.y, b3.z, b3.w}};
#pragma unroll
            for (int u = 0; u < 4; ++u)
#pragma unroll
                for (int j = 0; j < 4; ++j)
#pragma unroll
                    for (int c = 0; c < 4; ++c)
                        acc[j][c] = fmaf(av[j][u], bvv[u][c], acc[j][c]);
        }
#pragma unroll
        for (int j = 0; j < 4; ++j) {
            int n = base + ns * 4 + j;
            float4 o;
            float y0 = acc[j][0] * A[0] + C[0];
            float y1 = acc[j][1] * A[1] + C[1];
            float y2 = acc[j][2] * A[2] + C[2];
            float y3 = acc[j][3] * A[3] + C[3];
            o.x = y0 > 0.f ? y0 : 0.01f * y0;
            o.y = y1 > 0.f ? y1 : 0.01f * y1;
            o.z = y2 > 0.f ? y2 : 0.01f * y2;
            o.w = y3 > 0.f ? y3 : 0.01f * y3;
            *(float4*)&h[n * DIM + cg * 4] = o;
        }
    }
}

// ---------------- score dot products: t[n]=h.wr, s[n]=h.ws+b ----------------
__global__ __launch_bounds__(256) void dots_kernel(const float* __restrict__ h,
                                                   const float* __restrict__ wr,
                                                   const float* __restrict__ ws,
                                                   const float* __restrict__ pb,
                                                   float* __restrict__ tb,
                                                   float* __restrict__ sb) {
    int t = threadIdx.x;
    int wave = t >> 6, lane = t & 63;
    for (int n = blockIdx.x * 4 + wave; n < N_NODES; n += 4 * 4096) {
        float2 hv = *(const float2*)&h[n * DIM + lane * 2];
        float2 wrv = *(const float2*)&wr[lane * 2];
        float2 wsv = *(const float2*)&ws[lane * 2];
        float tr = hv.x * wrv.x + hv.y * wrv.y;
        float ts = hv.x * wsv.x + hv.y * wsv.y;
#pragma unroll
        for (int off = 32; off; off >>= 1) {
            tr += __shfl_xor(tr, off);
            ts += __shfl_xor(ts, off);
        }
        if (lane == 0) {
            tb[n] = tr;
            sb[n] = ts + pb[0];
        }
    }
}

__global__ void score_kernel(const int* __restrict__ rowptr, const int* __restrict__ csr_src,
                             const float* __restrict__ tb, float* __restrict__ sb) {
    int n = blockIdx.x * 256 + threadIdx.x;
    float s = sb[n];
    int e0 = rowptr[n], e1 = rowptr[n + 1];
    for (int e = e0; e < e1; ++e) s += tb[csr_src[e]];
    sb[n] = s;
}

// ---------------- per-graph top-K select + weighted pool ----------------
__global__ __launch_bounds__(1024) void topk_pool_kernel(const float* __restrict__ sb,
                                                         const float* __restrict__ h,
                                                         float* __restrict__ xg) {
    __shared__ unsigned su[NPG];       // 32 KB
    __shared__ int sel_n[KSEL];        // 16 KB
    __shared__ float sel_w[KSEL];      // 16 KB
    __shared__ float part[8 * DIM];    // 4 KB
    __shared__ int red[16];
    __shared__ int cnt_sh;
    __shared__ int list_cnt;

    int b = blockIdx.x, t = threadIdx.x;
    const float* sc = &sb[b * NPG];
    for (int i = t; i < NPG; i += 1024) {
        unsigned u = __float_as_uint(sc[i]);
        u = (u & 0x80000000u) ? ~u : (u | 0x80000000u);
        su[i] = u;
    }
    __syncthreads();

    // binary search: smallest v with count(su > v) < KSEL  ->  v is Kth largest
    unsigned lo = 0u, hi = 0xFFFFFFFFu;
    while (lo < hi) {
        unsigned mid = lo + ((hi - lo) >> 1);
        int c = 0;
        for (int i = t; i < NPG; i += 1024) c += (su[i] > mid) ? 1 : 0;
#pragma unroll
        for (int off = 32; off; off >>= 1) c += __shfl_xor(c, off);
        if ((t & 63) == 0) red[t >> 6] = c;
        __syncthreads();
        if (t == 0) {
            int tot = 0;
            for (int w = 0; w < 16; ++w) tot += red[w];
            cnt_sh = tot;
        }
        __syncthreads();
        int total = cnt_sh;
        __syncthreads();
        if (total < KSEL) hi = mid; else lo = mid + 1;
    }
    unsigned T = lo;

    // count strictly-greater to know how many ties to take
    {
        int c = 0;
        for (int i = t; i < NPG; i += 1024) c += (su[i] > T) ? 1 : 0;
#pragma unroll
        for (int off = 32; off; off >>= 1) c += __shfl_xor(c, off);
        if ((t & 63) == 0) red[t >> 6] = c;
        __syncthreads();
        if (t == 0) {
            int tot = 0;
            for (int w = 0; w < 16; ++w) tot += red[w];
            cnt_sh = tot;
            list_cnt = 0;
        }
        __syncthreads();
    }
    int need_eq = KSEL - cnt_sh;

    for (int i = t; i < NPG; i += 1024) {
        unsigned u = su[i];
        bool take = (u > T);
        if (!take && u == T) {
            int r = 0;
            for (int j = 0; j < i; ++j) r += (su[j] == T) ? 1 : 0;
            take = (r < need_eq);
        }
        if (take) {
            int p = atomicAdd(&list_cnt, 1);
            sel_n[p] = i;
            float f = (u & 0x80000000u) ? __uint_as_float(u & 0x7FFFFFFFu)
                                        : __uint_as_float(~u);
            sel_w[p] = tanhf(f);
        }
    }
    __syncthreads();

    // weighted sum of selected rows
    int d = t & 127, nl = t >> 7;
    float acc = 0.f;
    for (int i = nl; i < KSEL; i += 8)
        acc += h[(size_t)(b * NPG + sel_n[i]) * DIM + d] * sel_w[i];
    part[nl * DIM + d] = acc;
    __syncthreads();
    if (nl == 0) {
        float s = 0.f;
#pragma unroll
        for (int q = 0; q < 8; ++q) s += part[q * DIM + d];
        xg[b * DIM + d] = s;
    }
}

// ---------------- final MLP ----------------
__global__ __launch_bounds__(1024) void mlp_kernel(const float* __restrict__ xg,
                                                   const float* __restrict__ r1w,
                                                   const float* __restrict__ r1b,
                                                   const float* __restrict__ r2w,
                                                   const float* __restrict__ r2b,
                                                   float* __restrict__ out) {
    __shared__ float h1[16 * 64];
    int t = threadIdx.x;
    {
        int b = t >> 6, j = t & 63;
        float acc = r1b[j];
        for (int k = 0; k < DIM; ++k) acc += xg[b * DIM + k] * r1w[k * 64 + j];
        h1[b * 64 + j] = acc > 0.f ? acc : 0.01f * acc;
    }
    __syncthreads();
    if (t < 64) {
        int b = t >> 2, o = t & 3;
        float acc = r2b[o];
        for (int k = 0; k < 64; ++k) acc += h1[b * 64 + k] * r2w[k * 4 + o];
        out[b * 4 + o] = acc;
    }
}

extern "C" void kernel_launch(void* const* d_in, const int* in_sizes, int n_in,
                              void* d_out, int out_size, void* d_ws, size_t ws_size,
                              hipStream_t stream) {
    const float* x       = (const float*)d_in[0];
    const int*   ei      = (const int*)d_in[2];
    const float* node_w  = (const float*)d_in[3];
    const float* node_b  = (const float*)d_in[4];
    const float* conv_w  = (const float*)d_in[7];
    const float* conv_b  = (const float*)d_in[8];
    const float* bn_g    = (const float*)d_in[9];
    const float* bn_b    = (const float*)d_in[10];
    const float* bn_m    = (const float*)d_in[11];
    const float* bn_v    = (const float*)d_in[12];
    const float* pool_wr = (const float*)d_in[13];
    const float* pool_ws = (const float*)d_in[14];
    const float* pool_b  = (const float*)d_in[15];
    const float* r1_w    = (const float*)d_in[16];
    const float* r1_b    = (const float*)d_in[17];
    const float* r2_w    = (const float*)d_in[18];
    const float* r2_b    = (const float*)d_in[19];
    float* out = (float*)d_out;

    char* ws = (char*)d_ws;
    size_t off = 0;
    auto alloc = [&](size_t bytes) {
        void* p = ws + off;
        off = (off + bytes + 255) & ~(size_t)255;
        return p;
    };
    float* h       = (float*)alloc((size_t)N_NODES * DIM * 4);
    float* mbuf    = (float*)alloc((size_t)N_NODES * DIM * 4);
    int*   deg     = (int*)alloc((size_t)N_NODES * 4);
    int*   rowptr  = (int*)alloc((size_t)(N_NODES + 1) * 4);
    int*   cursor  = (int*)alloc((size_t)N_NODES * 4);
    float* dis     = (float*)alloc((size_t)N_NODES * 4);
    int*   csr_src = (int*)alloc((size_t)E_EDGES * 4);
    float* csr_cf  = (float*)alloc((size_t)E_EDGES * 4);
    float* tb      = (float*)alloc((size_t)N_NODES * 4);
    float* sb      = (float*)alloc((size_t)N_NODES * 4);
    float* xg      = (float*)alloc((size_t)NGRAPH * DIM * 4);

    hipMemsetAsync(deg, 0, (size_t)N_NODES * 4, stream);
    count_deg_kernel<<<E_EDGES / 256, 256, 0, stream>>>(ei, deg);
    scan_kernel<<<1, 1024, 0, stream>>>(deg, rowptr, cursor, dis);
    fill_csr_kernel<<<E_EDGES / 256, 256, 0, stream>>>(ei, cursor, dis, csr_src, csr_cf);
    embed_kernel<<<N_NODES / 32, 256, 0, stream>>>(x, node_w, node_b, h);

    for (int layer = 0; layer < 3; ++layer) {
        agg_kernel<<<8192, 256, 0, stream>>>(h, rowptr, csr_src, csr_cf, dis, mbuf);
        gemm_bn_kernel<<<N_NODES / 128, 256, 0, stream>>>(
            mbuf, conv_w + (size_t)layer * DIM * DIM, conv_b + layer * DIM,
            bn_g + layer * DIM, bn_b + layer * DIM, bn_m + layer * DIM,
            bn_v + layer * DIM, h);
    }

    dots_kernel<<<4096, 256, 0, stream>>>(h, pool_wr, pool_ws, pool_b, tb, sb);
    score_kernel<<<N_NODES / 256, 256, 0, stream>>>(rowptr, csr_src, tb, sb);
    topk_pool_kernel<<<NGRAPH, 1024, 0, stream>>>(sb, h, xg);
    mlp_kernel<<<1, 1024, 0, stream>>>(xg, r1_w, r1_b, r2_w, r2_b, out);
}

// Round 2
// 1122.039 us; speedup vs baseline: 1.1022x; 1.1022x over previous
//
#include <hip/hip_runtime.h>

#define N_NODES 131072
#define E_EDGES 524288
#define NGRAPH  16
#define NPG     8192
#define DIM     128
#define KSEL    4096

// ---------------- CSR build ----------------
__global__ void count_deg_kernel(const int* __restrict__ ei, int* __restrict__ deg) {
    int e = blockIdx.x * 256 + threadIdx.x;
    atomicAdd(&deg[ei[E_EDGES + e]], 1);
}

__global__ __launch_bounds__(1024) void scan_kernel(const int* __restrict__ deg,
                                                    int* __restrict__ rowptr,
                                                    int* __restrict__ cursor,
                                                    float* __restrict__ dis) {
    __shared__ int ssum[1024];
    int t = threadIdx.x;
    const int CH = N_NODES / 1024;  // 128
    int base = t * CH;
    int s = 0;
    for (int i = 0; i < CH; ++i) s += deg[base + i];
    ssum[t] = s;
    __syncthreads();
    for (int off = 1; off < 1024; off <<= 1) {
        int v = (t >= off) ? ssum[t - off] : 0;
        __syncthreads();
        ssum[t] += v;
        __syncthreads();
    }
    int running = ssum[t] - s;  // exclusive prefix
    for (int i = 0; i < CH; ++i) {
        int idx = base + i;
        int dg = deg[idx];
        rowptr[idx] = running;
        cursor[idx] = running;
        dis[idx] = rsqrtf((float)dg + 1.0f);
        running += dg;
    }
    if (t == 1023) rowptr[N_NODES] = running;
}

__global__ void fill_csr_kernel(const int* __restrict__ ei, int* __restrict__ cursor,
                                const float* __restrict__ dis, int* __restrict__ csr_src,
                                float* __restrict__ csr_coef) {
    int e = blockIdx.x * 256 + threadIdx.x;
    int s = ei[e];
    int d = ei[E_EDGES + e];
    int p = atomicAdd(&cursor[d], 1);
    csr_src[p] = s;
    csr_coef[p] = dis[s] * dis[d];
}

// ---------------- node embedding: h = x @ node_w + node_b ----------------
__global__ __launch_bounds__(256) void embed_kernel(const float* __restrict__ x,
                                                    const float* __restrict__ nw,
                                                    const float* __restrict__ nb,
                                                    float* __restrict__ h) {
    __shared__ float Wl[16 * DIM];
    int t = threadIdx.x;
    for (int i = t * 4; i < 16 * DIM; i += 1024)
        *(float4*)&Wl[i] = *(const float4*)&nw[i];
    __syncthreads();
    int d = t & 127, sub = t >> 7;
    float bias = nb[d];
    int base = blockIdx.x * 32;
    for (int k = 0; k < 16; ++k) {
        int n = base + k * 2 + sub;
        const float* xr = &x[n * 16];
        float acc = bias;
#pragma unroll
        for (int f = 0; f < 16; ++f) acc += xr[f] * Wl[f * DIM + d];
        h[n * DIM + d] = acc;
    }
}

// ---------------- sparse propagate: m = sum coef*h[src] + dis^2 * h ----------------
__global__ __launch_bounds__(256) void agg_kernel(const float* __restrict__ h,
                                                  const int* __restrict__ rowptr,
                                                  const int* __restrict__ csr_src,
                                                  const float* __restrict__ csr_coef,
                                                  const float* __restrict__ dis,
                                                  float* __restrict__ m) {
    int t = threadIdx.x;
    int d = t & 127;
    int sub = t >> 7;
    for (int np = blockIdx.x; np < N_NODES / 2; np += 8192) {
        int n = np * 2 + sub;
        float dn = dis[n];
        float acc = dn * dn * h[n * DIM + d];
        int e0 = rowptr[n], e1 = rowptr[n + 1];
        for (int e = e0; e < e1; ++e) {
            acc += csr_coef[e] * h[csr_src[e] * DIM + d];
        }
        m[n * DIM + d] = acc;
    }
}

// ---------------- dense: h = leaky(BN(m @ W + cb)) fused ----------------
__global__ __launch_bounds__(256) void gemm_bn_kernel(const float* __restrict__ m,
                                                      const float* __restrict__ W,
                                                      const float* __restrict__ cb,
                                                      const float* __restrict__ bg,
                                                      const float* __restrict__ bb,
                                                      const float* __restrict__ bm,
                                                      const float* __restrict__ bv,
                                                      float* __restrict__ h) {
    __shared__ float Wl[DIM * DIM];   // 64 KB
    __shared__ float Ml[32 * DIM];    // 16 KB
    int t = threadIdx.x;
    for (int i = t * 4; i < DIM * DIM; i += 1024)
        *(float4*)&Wl[i] = *(const float4*)&W[i];
    int cg = t & 31;   // column group (4 cols)
    int ns = t >> 5;   // node strip (4 nodes), 0..7
    float A[4], C[4];
#pragma unroll
    for (int c = 0; c < 4; ++c) {
        int d = cg * 4 + c;
        float inv = rsqrtf(bv[d] + 1e-5f);
        float a = bg[d] * inv;
        A[c] = a;
        C[c] = (cb[d] - bm[d]) * a + bb[d];
    }
    __syncthreads();
    for (int tile = 0; tile < 4; ++tile) {
        int base = (blockIdx.x * 4 + tile) * 32;
        __syncthreads();
        for (int i = t * 4; i < 32 * DIM; i += 1024)
            *(float4*)&Ml[i] = *(const float4*)&m[base * DIM + i];
        __syncthreads();
        float acc[4][4] = {{0.f}};
        for (int k = 0; k < DIM; k += 4) {
            float4 a0 = *(float4*)&Ml[(ns * 4 + 0) * DIM + k];
            float4 a1 = *(float4*)&Ml[(ns * 4 + 1) * DIM + k];
            float4 a2 = *(float4*)&Ml[(ns * 4 + 2) * DIM + k];
            float4 a3 = *(float4*)&Ml[(ns * 4 + 3) * DIM + k];
            float4 b0 = *(float4*)&Wl[(k + 0) * DIM + cg * 4];
            float4 b1 = *(float4*)&Wl[(k + 1) * DIM + cg * 4];
            float4 b2 = *(float4*)&Wl[(k + 2) * DIM + cg * 4];
            float4 b3 = *(float4*)&Wl[(k + 3) * DIM + cg * 4];
            float av[4][4] = {{a0.x, a0.y, a0.z, a0.w},
                              {a1.x, a1.y, a1.z, a1.w},
                              {a2.x, a2.y, a2.z, a2.w},
                              {a3.x, a3.y, a3.z, a3.w}};
            float bvv[4][4] = {{b0.x, b0.y, b0.z, b0.w},
                               {b1.x, b1.y, b1.z, b1.w},
                               {b2.x, b2.y, b2.z, b2.w},
                               {b3.x, b3.y, b3.z, b3.w}};
#pragma unroll
            for (int u = 0; u < 4; ++u)
#pragma unroll
                for (int j = 0; j < 4; ++j)
#pragma unroll
                    for (int c = 0; c < 4; ++c)
                        acc[j][c] = fmaf(av[j][u], bvv[u][c], acc[j][c]);
        }
#pragma unroll
        for (int j = 0; j < 4; ++j) {
            int n = base + ns * 4 + j;
            float4 o;
            float y0 = acc[j][0] * A[0] + C[0];
            float y1 = acc[j][1] * A[1] + C[1];
            float y2 = acc[j][2] * A[2] + C[2];
            float y3 = acc[j][3] * A[3] + C[3];
            o.x = y0 > 0.f ? y0 : 0.01f * y0;
            o.y = y1 > 0.f ? y1 : 0.01f * y1;
            o.z = y2 > 0.f ? y2 : 0.01f * y2;
            o.w = y3 > 0.f ? y3 : 0.01f * y3;
            *(float4*)&h[n * DIM + cg * 4] = o;
        }
    }
}

// ---------------- score dot products: t[n]=h.wr, s[n]=h.ws+b ----------------
__global__ __launch_bounds__(256) void dots_kernel(const float* __restrict__ h,
                                                   const float* __restrict__ wr,
                                                   const float* __restrict__ ws,
                                                   const float* __restrict__ pb,
                                                   float* __restrict__ tb,
                                                   float* __restrict__ sb) {
    int t = threadIdx.x;
    int wave = t >> 6, lane = t & 63;
    for (int n = blockIdx.x * 4 + wave; n < N_NODES; n += 4 * 4096) {
        float2 hv = *(const float2*)&h[n * DIM + lane * 2];
        float2 wrv = *(const float2*)&wr[lane * 2];
        float2 wsv = *(const float2*)&ws[lane * 2];
        float tr = hv.x * wrv.x + hv.y * wrv.y;
        float ts = hv.x * wsv.x + hv.y * wsv.y;
#pragma unroll
        for (int off = 32; off; off >>= 1) {
            tr += __shfl_xor(tr, off);
            ts += __shfl_xor(ts, off);
        }
        if (lane == 0) {
            tb[n] = tr;
            sb[n] = ts + pb[0];
        }
    }
}

__global__ void score_kernel(const int* __restrict__ rowptr, const int* __restrict__ csr_src,
                             const float* __restrict__ tb, float* __restrict__ sb) {
    int n = blockIdx.x * 256 + threadIdx.x;
    float s = sb[n];
    int e0 = rowptr[n], e1 = rowptr[n + 1];
    for (int e = e0; e < e1; ++e) s += tb[csr_src[e]];
    sb[n] = s;
}

// ---------------- per-graph top-K threshold + per-node pooling weight ----------------
// wsel[n] = tanh(score[n]) if node n is among the K largest scores of its graph
//           (ties broken by smallest index, matching jax.lax.top_k), else 0.
__global__ __launch_bounds__(256) void select_kernel(const float* __restrict__ sb,
                                                     float* __restrict__ wsel) {
    __shared__ unsigned su[NPG];   // 32 KB
    __shared__ int red[4];
    __shared__ int cnt_sh;

    int b = blockIdx.x, t = threadIdx.x;
    const float* sc = &sb[b * NPG];
    for (int i = t; i < NPG; i += 256) {
        unsigned u = __float_as_uint(sc[i]);
        u = (u & 0x80000000u) ? ~u : (u | 0x80000000u);
        su[i] = u;
    }
    __syncthreads();

    const uint4* su4 = (const uint4*)su;
    // binary search: smallest v with count(su > v) < KSEL  ->  v = Kth largest key
    unsigned lo = 0u, hi = 0xFFFFFFFFu;
    while (lo < hi) {
        unsigned mid = lo + ((hi - lo) >> 1);
        int c = 0;
        for (int i = t; i < NPG / 4; i += 256) {
            uint4 v = su4[i];
            c += (v.x > mid) + (v.y > mid) + (v.z > mid) + (v.w > mid);
        }
#pragma unroll
        for (int off = 32; off; off >>= 1) c += __shfl_xor(c, off);
        if ((t & 63) == 0) red[t >> 6] = c;
        __syncthreads();
        if (t == 0) cnt_sh = red[0] + red[1] + red[2] + red[3];
        __syncthreads();
        int total = cnt_sh;
        __syncthreads();
        if (total < KSEL) hi = mid; else lo = mid + 1;
    }
    unsigned T = lo;

    // count strictly-greater -> how many ==T ties to take (in index order)
    {
        int c = 0;
        for (int i = t; i < NPG / 4; i += 256) {
            uint4 v = su4[i];
            c += (v.x > T) + (v.y > T) + (v.z > T) + (v.w > T);
        }
#pragma unroll
        for (int off = 32; off; off >>= 1) c += __shfl_xor(c, off);
        if ((t & 63) == 0) red[t >> 6] = c;
        __syncthreads();
        if (t == 0) cnt_sh = red[0] + red[1] + red[2] + red[3];
        __syncthreads();
    }
    int need_eq = KSEL - cnt_sh;

    for (int i = t; i < NPG; i += 256) {
        unsigned u = su[i];
        bool take = (u > T);
        if (!take && u == T) {
            int r = 0;
            for (int j = 0; j < i; ++j) r += (su[j] == T) ? 1 : 0;
            take = (r < need_eq);
        }
        float w = 0.f;
        if (take) {
            float f = (u & 0x80000000u) ? __uint_as_float(u & 0x7FFFFFFFu)
                                        : __uint_as_float(~u);
            w = tanhf(f);
        }
        wsel[b * NPG + i] = w;
    }
}

// ---------------- weighted pool: part[b][chunk][d] = sum wsel*h (streaming) ----------------
__global__ __launch_bounds__(256) void pool_kernel(const float* __restrict__ wsel,
                                                   const float* __restrict__ h,
                                                   float* __restrict__ part) {
    int blk = blockIdx.x;
    int b = blk >> 5;          // graph
    int ch = blk & 31;         // chunk of 256 nodes
    int t = threadIdx.x;
    int nl = t >> 6;           // wave id 0..3
    int l = t & 63;            // lane -> dims l*2, l*2+1
    int n0 = b * NPG + ch * 256;
    float ax = 0.f, ay = 0.f;
    for (int i = nl; i < 256; i += 4) {
        int n = n0 + i;
        float w = wsel[n];     // wave-uniform broadcast
        if (w != 0.f) {        // uniform branch: skip unselected rows
            float2 v = *(const float2*)&h[(size_t)n * DIM + l * 2];
            ax += w * v.x;
            ay += w * v.y;
        }
    }
    __shared__ float pp[4][DIM];
    pp[nl][l * 2] = ax;
    pp[nl][l * 2 + 1] = ay;
    __syncthreads();
    if (t < DIM) {
        float s = pp[0][t] + pp[1][t] + pp[2][t] + pp[3][t];
        part[((size_t)b * 32 + ch) * DIM + t] = s;
    }
}

__global__ void pool_reduce_kernel(const float* __restrict__ part,
                                   float* __restrict__ xg) {
    int b = blockIdx.x, d = threadIdx.x;
    float s = 0.f;
    for (int c = 0; c < 32; ++c) s += part[((size_t)b * 32 + c) * DIM + d];
    xg[b * DIM + d] = s;
}

// ---------------- final MLP ----------------
__global__ __launch_bounds__(1024) void mlp_kernel(const float* __restrict__ xg,
                                                   const float* __restrict__ r1w,
                                                   const float* __restrict__ r1b,
                                                   const float* __restrict__ r2w,
                                                   const float* __restrict__ r2b,
                                                   float* __restrict__ out) {
    __shared__ float h1[16 * 64];
    int t = threadIdx.x;
    {
        int b = t >> 6, j = t & 63;
        float acc = r1b[j];
        for (int k = 0; k < DIM; ++k) acc += xg[b * DIM + k] * r1w[k * 64 + j];
        h1[b * 64 + j] = acc > 0.f ? acc : 0.01f * acc;
    }
    __syncthreads();
    if (t < 64) {
        int b = t >> 2, o = t & 3;
        float acc = r2b[o];
        for (int k = 0; k < 64; ++k) acc += h1[b * 64 + k] * r2w[k * 4 + o];
        out[b * 4 + o] = acc;
    }
}

extern "C" void kernel_launch(void* const* d_in, const int* in_sizes, int n_in,
                              void* d_out, int out_size, void* d_ws, size_t ws_size,
                              hipStream_t stream) {
    const float* x       = (const float*)d_in[0];
    const int*   ei      = (const int*)d_in[2];
    const float* node_w  = (const float*)d_in[3];
    const float* node_b  = (const float*)d_in[4];
    const float* conv_w  = (const float*)d_in[7];
    const float* conv_b  = (const float*)d_in[8];
    const float* bn_g    = (const float*)d_in[9];
    const float* bn_b    = (const float*)d_in[10];
    const float* bn_m    = (const float*)d_in[11];
    const float* bn_v    = (const float*)d_in[12];
    const float* pool_wr = (const float*)d_in[13];
    const float* pool_ws = (const float*)d_in[14];
    const float* pool_b  = (const float*)d_in[15];
    const float* r1_w    = (const float*)d_in[16];
    const float* r1_b    = (const float*)d_in[17];
    const float* r2_w    = (const float*)d_in[18];
    const float* r2_b    = (const float*)d_in[19];
    float* out = (float*)d_out;

    char* ws = (char*)d_ws;
    size_t off = 0;
    auto alloc = [&](size_t bytes) {
        void* p = ws + off;
        off = (off + bytes + 255) & ~(size_t)255;
        return p;
    };
    float* h       = (float*)alloc((size_t)N_NODES * DIM * 4);
    float* mbuf    = (float*)alloc((size_t)N_NODES * DIM * 4);
    int*   deg     = (int*)alloc((size_t)N_NODES * 4);
    int*   rowptr  = (int*)alloc((size_t)(N_NODES + 1) * 4);
    int*   cursor  = (int*)alloc((size_t)N_NODES * 4);
    float* dis     = (float*)alloc((size_t)N_NODES * 4);
    int*   csr_src = (int*)alloc((size_t)E_EDGES * 4);
    float* csr_cf  = (float*)alloc((size_t)E_EDGES * 4);
    float* tb      = (float*)alloc((size_t)N_NODES * 4);
    float* sb      = (float*)alloc((size_t)N_NODES * 4);
    float* wsel    = (float*)alloc((size_t)N_NODES * 4);
    float* part    = (float*)alloc((size_t)NGRAPH * 32 * DIM * 4);
    float* xg      = (float*)alloc((size_t)NGRAPH * DIM * 4);

    hipMemsetAsync(deg, 0, (size_t)N_NODES * 4, stream);
    count_deg_kernel<<<E_EDGES / 256, 256, 0, stream>>>(ei, deg);
    scan_kernel<<<1, 1024, 0, stream>>>(deg, rowptr, cursor, dis);
    fill_csr_kernel<<<E_EDGES / 256, 256, 0, stream>>>(ei, cursor, dis, csr_src, csr_cf);
    embed_kernel<<<N_NODES / 32, 256, 0, stream>>>(x, node_w, node_b, h);

    for (int layer = 0; layer < 3; ++layer) {
        agg_kernel<<<8192, 256, 0, stream>>>(h, rowptr, csr_src, csr_cf, dis, mbuf);
        gemm_bn_kernel<<<N_NODES / 128, 256, 0, stream>>>(
            mbuf, conv_w + (size_t)layer * DIM * DIM, conv_b + layer * DIM,
            bn_g + layer * DIM, bn_b + layer * DIM, bn_m + layer * DIM,
            bn_v + layer * DIM, h);
    }

    dots_kernel<<<4096, 256, 0, stream>>>(h, pool_wr, pool_ws, pool_b, tb, sb);
    score_kernel<<<N_NODES / 256, 256, 0, stream>>>(rowptr, csr_src, tb, sb);
    select_kernel<<<NGRAPH, 256, 0, stream>>>(sb, wsel);
    pool_kernel<<<NGRAPH * 32, 256, 0, stream>>>(wsel, h, part);
    pool_reduce_kernel<<<NGRAPH, DIM, 0, stream>>>(part, xg);
    mlp_kernel<<<1, 1024, 0, stream>>>(xg, r1_w, r1_b, r2_w, r2_b, out);
}

// Round 3
// 847.205 us; speedup vs baseline: 1.4597x; 1.3244x over previous
//
#include <hip/hip_runtime.h>

#define N_NODES 131072
#define E_EDGES 524288
#define NGRAPH  16
#define NPG     8192
#define DIM     128
#define KSEL    4096

// ---------------- CSR build ----------------
__global__ void count_deg_kernel(const int* __restrict__ ei, int* __restrict__ deg) {
    int e = blockIdx.x * 256 + threadIdx.x;
    atomicAdd(&deg[ei[E_EDGES + e]], 1);
}

__global__ __launch_bounds__(1024) void scan_kernel(const int* __restrict__ deg,
                                                    int* __restrict__ rowptr,
                                                    int* __restrict__ cursor,
                                                    float* __restrict__ dis) {
    __shared__ int ssum[1024];
    int t = threadIdx.x;
    const int CH = N_NODES / 1024;  // 128
    int base = t * CH;
    int s = 0;
    for (int i = 0; i < CH; ++i) s += deg[base + i];
    ssum[t] = s;
    __syncthreads();
    for (int off = 1; off < 1024; off <<= 1) {
        int v = (t >= off) ? ssum[t - off] : 0;
        __syncthreads();
        ssum[t] += v;
        __syncthreads();
    }
    int running = ssum[t] - s;  // exclusive prefix
    for (int i = 0; i < CH; ++i) {
        int idx = base + i;
        int dg = deg[idx];
        rowptr[idx] = running;
        cursor[idx] = running;
        dis[idx] = rsqrtf((float)dg + 1.0f);
        running += dg;
    }
    if (t == 1023) rowptr[N_NODES] = running;
}

__global__ void fill_csr_kernel(const int* __restrict__ ei, int* __restrict__ cursor,
                                const float* __restrict__ dis, int* __restrict__ csr_src,
                                float* __restrict__ csr_coef) {
    int e = blockIdx.x * 256 + threadIdx.x;
    int s = ei[e];
    int d = ei[E_EDGES + e];
    int p = atomicAdd(&cursor[d], 1);
    csr_src[p] = s;
    csr_coef[p] = dis[s] * dis[d];
}

// ---------------- node embedding: h = x @ node_w + node_b ----------------
__global__ __launch_bounds__(256) void embed_kernel(const float* __restrict__ x,
                                                    const float* __restrict__ nw,
                                                    const float* __restrict__ nb,
                                                    float* __restrict__ h) {
    __shared__ float Wl[16 * DIM];
    int t = threadIdx.x;
    for (int i = t * 4; i < 16 * DIM; i += 1024)
        *(float4*)&Wl[i] = *(const float4*)&nw[i];
    __syncthreads();
    int d = t & 127, sub = t >> 7;
    float bias = nb[d];
    int base = blockIdx.x * 32;
    for (int k = 0; k < 16; ++k) {
        int n = base + k * 2 + sub;
        const float* xr = &x[n * 16];
        float acc = bias;
#pragma unroll
        for (int f = 0; f < 16; ++f) acc += xr[f] * Wl[f * DIM + d];
        h[n * DIM + d] = acc;
    }
}

// ---------------- sparse propagate: m = sum coef*h[src] + dis^2 * h ----------------
__global__ __launch_bounds__(256) void agg_kernel(const float* __restrict__ h,
                                                  const int* __restrict__ rowptr,
                                                  const int* __restrict__ csr_src,
                                                  const float* __restrict__ csr_coef,
                                                  const float* __restrict__ dis,
                                                  float* __restrict__ m) {
    int t = threadIdx.x;
    int d = t & 127;
    int sub = t >> 7;
    for (int np = blockIdx.x; np < N_NODES / 2; np += 8192) {
        int n = np * 2 + sub;
        float dn = dis[n];
        float acc = dn * dn * h[n * DIM + d];
        int e0 = rowptr[n], e1 = rowptr[n + 1];
        for (int e = e0; e < e1; ++e) {
            acc += csr_coef[e] * h[csr_src[e] * DIM + d];
        }
        m[n * DIM + d] = acc;
    }
}

// ---------------- dense: h = leaky(BN(m @ W + cb)) fused ----------------
__global__ __launch_bounds__(256) void gemm_bn_kernel(const float* __restrict__ m,
                                                      const float* __restrict__ W,
                                                      const float* __restrict__ cb,
                                                      const float* __restrict__ bg,
                                                      const float* __restrict__ bb,
                                                      const float* __restrict__ bm,
                                                      const float* __restrict__ bv,
                                                      float* __restrict__ h) {
    __shared__ float Wl[DIM * DIM];   // 64 KB
    __shared__ float Ml[32 * DIM];    // 16 KB
    int t = threadIdx.x;
    for (int i = t * 4; i < DIM * DIM; i += 1024)
        *(float4*)&Wl[i] = *(const float4*)&W[i];
    int cg = t & 31;   // column group (4 cols)
    int ns = t >> 5;   // node strip (4 nodes), 0..7
    float A[4], C[4];
#pragma unroll
    for (int c = 0; c < 4; ++c) {
        int d = cg * 4 + c;
        float inv = rsqrtf(bv[d] + 1e-5f);
        float a = bg[d] * inv;
        A[c] = a;
        C[c] = (cb[d] - bm[d]) * a + bb[d];
    }
    __syncthreads();
    for (int tile = 0; tile < 4; ++tile) {
        int base = (blockIdx.x * 4 + tile) * 32;
        __syncthreads();
        for (int i = t * 4; i < 32 * DIM; i += 1024)
            *(float4*)&Ml[i] = *(const float4*)&m[base * DIM + i];
        __syncthreads();
        float acc[4][4] = {{0.f}};
        for (int k = 0; k < DIM; k += 4) {
            float4 a0 = *(float4*)&Ml[(ns * 4 + 0) * DIM + k];
            float4 a1 = *(float4*)&Ml[(ns * 4 + 1) * DIM + k];
            float4 a2 = *(float4*)&Ml[(ns * 4 + 2) * DIM + k];
            float4 a3 = *(float4*)&Ml[(ns * 4 + 3) * DIM + k];
            float4 b0 = *(float4*)&Wl[(k + 0) * DIM + cg * 4];
            float4 b1 = *(float4*)&Wl[(k + 1) * DIM + cg * 4];
            float4 b2 = *(float4*)&Wl[(k + 2) * DIM + cg * 4];
            float4 b3 = *(float4*)&Wl[(k + 3) * DIM + cg * 4];
            float av[4][4] = {{a0.x, a0.y, a0.z, a0.w},
                              {a1.x, a1.y, a1.z, a1.w},
                              {a2.x, a2.y, a2.z, a2.w},
                              {a3.x, a3.y, a3.z, a3.w}};
            float bvv[4][4] = {{b0.x, b0.y, b0.z, b0.w},
                               {b1.x, b1.y, b1.z, b1.w},
                               {b2.x, b2.y, b2.z, b2.w},
                               {b3.x, b3.y, b3.z, b3.w}};
#pragma unroll
            for (int u = 0; u < 4; ++u)
#pragma unroll
                for (int j = 0; j < 4; ++j)
#pragma unroll
                    for (int c = 0; c < 4; ++c)
                        acc[j][c] = fmaf(av[j][u], bvv[u][c], acc[j][c]);
        }
#pragma unroll
        for (int j = 0; j < 4; ++j) {
            int n = base + ns * 4 + j;
            float4 o;
            float y0 = acc[j][0] * A[0] + C[0];
            float y1 = acc[j][1] * A[1] + C[1];
            float y2 = acc[j][2] * A[2] + C[2];
            float y3 = acc[j][3] * A[3] + C[3];
            o.x = y0 > 0.f ? y0 : 0.01f * y0;
            o.y = y1 > 0.f ? y1 : 0.01f * y1;
            o.z = y2 > 0.f ? y2 : 0.01f * y2;
            o.w = y3 > 0.f ? y3 : 0.01f * y3;
            *(float4*)&h[n * DIM + cg * 4] = o;
        }
    }
}

// ---------------- score dot products: t[n]=h.wr, s[n]=h.ws+b ----------------
__global__ __launch_bounds__(256) void dots_kernel(const float* __restrict__ h,
                                                   const float* __restrict__ wr,
                                                   const float* __restrict__ ws,
                                                   const float* __restrict__ pb,
                                                   float* __restrict__ tb,
                                                   float* __restrict__ sb) {
    int t = threadIdx.x;
    int wave = t >> 6, lane = t & 63;
    for (int n = blockIdx.x * 4 + wave; n < N_NODES; n += 4 * 4096) {
        float2 hv = *(const float2*)&h[n * DIM + lane * 2];
        float2 wrv = *(const float2*)&wr[lane * 2];
        float2 wsv = *(const float2*)&ws[lane * 2];
        float tr = hv.x * wrv.x + hv.y * wrv.y;
        float ts = hv.x * wsv.x + hv.y * wsv.y;
#pragma unroll
        for (int off = 32; off; off >>= 1) {
            tr += __shfl_xor(tr, off);
            ts += __shfl_xor(ts, off);
        }
        if (lane == 0) {
            tb[n] = tr;
            sb[n] = ts + pb[0];
        }
    }
}

__global__ void score_kernel(const int* __restrict__ rowptr, const int* __restrict__ csr_src,
                             const float* __restrict__ tb, float* __restrict__ sb) {
    int n = blockIdx.x * 256 + threadIdx.x;
    float s = sb[n];
    int e0 = rowptr[n], e1 = rowptr[n + 1];
    for (int e = e0; e < e1; ++e) s += tb[csr_src[e]];
    sb[n] = s;
}

// ---------------- per-graph top-K via 4-pass radix select (no serial chains) ----
// wsel[n] = tanh(score[n]) if node n is among the K largest scores of its graph
//           (ties broken by smallest index, matching jax.lax.top_k), else 0.
__global__ __launch_bounds__(256) void select_kernel(const float* __restrict__ sb,
                                                     float* __restrict__ wsel) {
    __shared__ unsigned su[NPG];   // 32 KB
    __shared__ int hist[256];
    __shared__ int wsum[4];
    __shared__ unsigned pref_sh;
    __shared__ int kneed_sh;

    int b = blockIdx.x, t = threadIdx.x;
    int lane = t & 63, wv = t >> 6;
    const float* sc = &sb[b * NPG];
    for (int i = t; i < NPG; i += 256) {
        unsigned u = __float_as_uint(sc[i]);
        u = (u & 0x80000000u) ? ~u : (u | 0x80000000u);
        su[i] = u;
    }
    if (t == 0) { pref_sh = 0u; kneed_sh = KSEL; }
    __syncthreads();

    // radix select, MSB -> LSB, 8 bits per pass
    for (int p = 3; p >= 0; --p) {
        hist[t] = 0;
        __syncthreads();
        unsigned pref = pref_sh;
        int kneed = kneed_sh;
        int shift = p * 8;
        unsigned maskHi = (p == 3) ? 0u : (0xFFFFFFFFu << (shift + 8));
        for (int i = t; i < NPG; i += 256) {
            unsigned u = su[i];
            if ((u & maskHi) == (pref & maskHi))
                atomicAdd(&hist[(u >> shift) & 0xFFu], 1);
        }
        __syncthreads();
        // block-wide inclusive prefix of hist over bin index t
        int x = hist[t];
#pragma unroll
        for (int off = 1; off < 64; off <<= 1) {
            int y = __shfl_up(x, off);
            if (lane >= off) x += y;
        }
        if (lane == 63) wsum[wv] = x;
        __syncthreads();
        int add = 0, tot = 0;
#pragma unroll
        for (int j = 0; j < 4; ++j) {
            int v = wsum[j];
            tot += v;
            if (j < wv) add += v;
        }
        int psum = x + add;        // inclusive prefix up to and including bin t
        int cnt_gt = tot - psum;   // matching elems with digit > t
        int myh = psum - (add + (x - hist[t])) ; // == hist[t]
        __syncthreads();
        if (cnt_gt < kneed && cnt_gt + myh >= kneed) {  // unique digit
            pref_sh = (pref & maskHi) | ((unsigned)t << shift);
            kneed_sh = kneed - cnt_gt;
        }
        __syncthreads();
    }
    unsigned T = pref_sh;
    int need_eq = kneed_sh;  // # of ==T elements to take, in index order

    // parallel tie-rank: thread t owns su[t*32 .. t*32+31]
    int base = t * 32;
    int local = 0;
#pragma unroll
    for (int k = 0; k < 32; ++k) local += (su[base + k] == T) ? 1 : 0;
    int x = local;
#pragma unroll
    for (int off = 1; off < 64; off <<= 1) {
        int y = __shfl_up(x, off);
        if (lane >= off) x += y;
    }
    if (lane == 63) wsum[wv] = x;
    __syncthreads();
    int add = 0;
#pragma unroll
    for (int j = 0; j < 4; ++j)
        if (j < wv) add += wsum[j];
    int rank = (x - local) + add;  // exclusive prefix of ==T count before this chunk
#pragma unroll
    for (int k = 0; k < 32; ++k) {
        unsigned u = su[base + k];
        bool take = (u > T);
        if (u == T) { take = (rank < need_eq); ++rank; }
        float w = 0.f;
        if (take) {
            float f = (u & 0x80000000u) ? __uint_as_float(u & 0x7FFFFFFFu)
                                        : __uint_as_float(~u);
            w = tanhf(f);
        }
        wsel[b * NPG + base + k] = w;
    }
}

// ---------------- weighted pool: part[b][chunk][d] = sum wsel*h (streaming) ----------------
__global__ __launch_bounds__(256) void pool_kernel(const float* __restrict__ wsel,
                                                   const float* __restrict__ h,
                                                   float* __restrict__ part) {
    int blk = blockIdx.x;
    int b = blk >> 5;          // graph
    int ch = blk & 31;         // chunk of 256 nodes
    int t = threadIdx.x;
    int nl = t >> 6;           // wave id 0..3
    int l = t & 63;            // lane -> dims l*2, l*2+1
    int n0 = b * NPG + ch * 256;
    float ax = 0.f, ay = 0.f;
    for (int i = nl; i < 256; i += 4) {
        int n = n0 + i;
        float w = wsel[n];     // wave-uniform broadcast
        if (w != 0.f) {        // uniform branch: skip unselected rows
            float2 v = *(const float2*)&h[(size_t)n * DIM + l * 2];
            ax += w * v.x;
            ay += w * v.y;
        }
    }
    __shared__ float pp[4][DIM];
    pp[nl][l * 2] = ax;
    pp[nl][l * 2 + 1] = ay;
    __syncthreads();
    if (t < DIM) {
        float s = pp[0][t] + pp[1][t] + pp[2][t] + pp[3][t];
        part[((size_t)b * 32 + ch) * DIM + t] = s;
    }
}

__global__ void pool_reduce_kernel(const float* __restrict__ part,
                                   float* __restrict__ xg) {
    int b = blockIdx.x, d = threadIdx.x;
    float s = 0.f;
    for (int c = 0; c < 32; ++c) s += part[((size_t)b * 32 + c) * DIM + d];
    xg[b * DIM + d] = s;
}

// ---------------- final MLP ----------------
__global__ __launch_bounds__(1024) void mlp_kernel(const float* __restrict__ xg,
                                                   const float* __restrict__ r1w,
                                                   const float* __restrict__ r1b,
                                                   const float* __restrict__ r2w,
                                                   const float* __restrict__ r2b,
                                                   float* __restrict__ out) {
    __shared__ float h1[16 * 64];
    int t = threadIdx.x;
    {
        int b = t >> 6, j = t & 63;
        float acc = r1b[j];
        for (int k = 0; k < DIM; ++k) acc += xg[b * DIM + k] * r1w[k * 64 + j];
        h1[b * 64 + j] = acc > 0.f ? acc : 0.01f * acc;
    }
    __syncthreads();
    if (t < 64) {
        int b = t >> 2, o = t & 3;
        float acc = r2b[o];
        for (int k = 0; k < 64; ++k) acc += h1[b * 64 + k] * r2w[k * 4 + o];
        out[b * 4 + o] = acc;
    }
}

extern "C" void kernel_launch(void* const* d_in, const int* in_sizes, int n_in,
                              void* d_out, int out_size, void* d_ws, size_t ws_size,
                              hipStream_t stream) {
    const float* x       = (const float*)d_in[0];
    const int*   ei      = (const int*)d_in[2];
    const float* node_w  = (const float*)d_in[3];
    const float* node_b  = (const float*)d_in[4];
    const float* conv_w  = (const float*)d_in[7];
    const float* conv_b  = (const float*)d_in[8];
    const float* bn_g    = (const float*)d_in[9];
    const float* bn_b    = (const float*)d_in[10];
    const float* bn_m    = (const float*)d_in[11];
    const float* bn_v    = (const float*)d_in[12];
    const float* pool_wr = (const float*)d_in[13];
    const float* pool_ws = (const float*)d_in[14];
    const float* pool_b  = (const float*)d_in[15];
    const float* r1_w    = (const float*)d_in[16];
    const float* r1_b    = (const float*)d_in[17];
    const float* r2_w    = (const float*)d_in[18];
    const float* r2_b    = (const float*)d_in[19];
    float* out = (float*)d_out;

    char* ws = (char*)d_ws;
    size_t off = 0;
    auto alloc = [&](size_t bytes) {
        void* p = ws + off;
        off = (off + bytes + 255) & ~(size_t)255;
        return p;
    };
    float* h       = (float*)alloc((size_t)N_NODES * DIM * 4);
    float* mbuf    = (float*)alloc((size_t)N_NODES * DIM * 4);
    int*   deg     = (int*)alloc((size_t)N_NODES * 4);
    int*   rowptr  = (int*)alloc((size_t)(N_NODES + 1) * 4);
    int*   cursor  = (int*)alloc((size_t)N_NODES * 4);
    float* dis     = (float*)alloc((size_t)N_NODES * 4);
    int*   csr_src = (int*)alloc((size_t)E_EDGES * 4);
    float* csr_cf  = (float*)alloc((size_t)E_EDGES * 4);
    float* tb      = (float*)alloc((size_t)N_NODES * 4);
    float* sb      = (float*)alloc((size_t)N_NODES * 4);
    float* wsel    = (float*)alloc((size_t)N_NODES * 4);
    float* part    = (float*)alloc((size_t)NGRAPH * 32 * DIM * 4);
    float* xg      = (float*)alloc((size_t)NGRAPH * DIM * 4);

    hipMemsetAsync(deg, 0, (size_t)N_NODES * 4, stream);
    count_deg_kernel<<<E_EDGES / 256, 256, 0, stream>>>(ei, deg);
    scan_kernel<<<1, 1024, 0, stream>>>(deg, rowptr, cursor, dis);
    fill_csr_kernel<<<E_EDGES / 256, 256, 0, stream>>>(ei, cursor, dis, csr_src, csr_cf);
    embed_kernel<<<N_NODES / 32, 256, 0, stream>>>(x, node_w, node_b, h);

    for (int layer = 0; layer < 3; ++layer) {
        agg_kernel<<<8192, 256, 0, stream>>>(h, rowptr, csr_src, csr_cf, dis, mbuf);
        gemm_bn_kernel<<<N_NODES / 128, 256, 0, stream>>>(
            mbuf, conv_w + (size_t)layer * DIM * DIM, conv_b + layer * DIM,
            bn_g + layer * DIM, bn_b + layer * DIM, bn_m + layer * DIM,
            bn_v + layer * DIM, h);
    }

    dots_kernel<<<4096, 256, 0, stream>>>(h, pool_wr, pool_ws, pool_b, tb, sb);
    score_kernel<<<N_NODES / 256, 256, 0, stream>>>(rowptr, csr_src, tb, sb);
    select_kernel<<<NGRAPH, 256, 0, stream>>>(sb, wsel);
    pool_kernel<<<NGRAPH * 32, 256, 0, stream>>>(wsel, h, part);
    pool_reduce_kernel<<<NGRAPH, DIM, 0, stream>>>(part, xg);
    mlp_kernel<<<1, 1024, 0, stream>>>(xg, r1_w, r1_b, r2_w, r2_b, out);
}

// Round 4
// 667.459 us; speedup vs baseline: 1.8528x; 1.2693x over previous
//
#include <hip/hip_runtime.h>

#define N_NODES 131072
#define E_EDGES 524288
#define NGRAPH  16
#define NPG     8192
#define DIM     128
#define KSEL    4096

typedef float v2f __attribute__((ext_vector_type(2)));

// ---------------- CSR build ----------------
__global__ void count_deg_kernel(const int* __restrict__ ei, int* __restrict__ deg) {
    int e = blockIdx.x * 256 + threadIdx.x;
    atomicAdd(&deg[ei[E_EDGES + e]], 1);
}

__global__ __launch_bounds__(1024) void scan_kernel(const int* __restrict__ deg,
                                                    int* __restrict__ rowptr,
                                                    int* __restrict__ cursor,
                                                    float* __restrict__ dis) {
    __shared__ int ssum[1024];
    int t = threadIdx.x;
    const int CH = N_NODES / 1024;  // 128
    int base = t * CH;
    int s = 0;
    for (int i = 0; i < CH; ++i) s += deg[base + i];
    ssum[t] = s;
    __syncthreads();
    for (int off = 1; off < 1024; off <<= 1) {
        int v = (t >= off) ? ssum[t - off] : 0;
        __syncthreads();
        ssum[t] += v;
        __syncthreads();
    }
    int running = ssum[t] - s;  // exclusive prefix
    for (int i = 0; i < CH; ++i) {
        int idx = base + i;
        int dg = deg[idx];
        rowptr[idx] = running;
        cursor[idx] = running;
        dis[idx] = rsqrtf((float)dg + 1.0f);
        running += dg;
    }
    if (t == 1023) rowptr[N_NODES] = running;
}

__global__ void fill_csr_kernel(const int* __restrict__ ei, int* __restrict__ cursor,
                                const float* __restrict__ dis, int* __restrict__ csr_src,
                                float* __restrict__ csr_coef) {
    int e = blockIdx.x * 256 + threadIdx.x;
    int s = ei[e];
    int d = ei[E_EDGES + e];
    int p = atomicAdd(&cursor[d], 1);
    csr_src[p] = s;
    csr_coef[p] = dis[s] * dis[d];
}

// ---------------- node embedding: h = x @ node_w + node_b ----------------
__global__ __launch_bounds__(256) void embed_kernel(const float* __restrict__ x,
                                                    const float* __restrict__ nw,
                                                    const float* __restrict__ nb,
                                                    float* __restrict__ h) {
    __shared__ float Wl[16 * DIM];
    int t = threadIdx.x;
    for (int i = t * 4; i < 16 * DIM; i += 1024)
        *(float4*)&Wl[i] = *(const float4*)&nw[i];
    __syncthreads();
    int d = t & 127, sub = t >> 7;
    float bias = nb[d];
    int base = blockIdx.x * 32;
    for (int k = 0; k < 16; ++k) {
        int n = base + k * 2 + sub;
        const float* xr = &x[n * 16];
        float acc = bias;
#pragma unroll
        for (int f = 0; f < 16; ++f) acc += xr[f] * Wl[f * DIM + d];
        h[n * DIM + d] = acc;
    }
}

// ---------------- sparse propagate: m = sum coef*h[src] + dis^2 * h ----------------
// XCD-affine: blockIdx&7 selects the XCD (round-robin dispatch); graph g's
// blocks all land on XCD g%8 so the 4 MB h-slice stays L2-resident. Low block
// IDs cover graphs 0-7, high IDs graphs 8-15 (temporal phase split).
// Wave-per-node: lane l holds dims 2l,2l+1 (one dwordx2 per gathered row).
__global__ __launch_bounds__(256) void agg_kernel(const float* __restrict__ h,
                                                  const int* __restrict__ rowptr,
                                                  const int* __restrict__ csr_src,
                                                  const float* __restrict__ csr_coef,
                                                  const float* __restrict__ dis,
                                                  float* __restrict__ m) {
    int bb = blockIdx.x;
    int xslot = bb & 7;
    int c = bb >> 3;                 // 0..1023
    int g = xslot + ((c >= 512) ? 8 : 0);
    int chunk = c & 511;             // 0..511
    int t = threadIdx.x;
    int nl = t >> 6, l = t & 63;
    int nbase = g * NPG + chunk * 16;
#pragma unroll
    for (int it = 0; it < 4; ++it) {
        int n = nbase + it * 4 + nl;
        float dn = dis[n];
        float2 hv = *(const float2*)&h[(size_t)n * DIM + l * 2];
        float ax = dn * dn * hv.x;
        float ay = dn * dn * hv.y;
        int e0 = rowptr[n], e1 = rowptr[n + 1];
        for (int e = e0; e < e1; ++e) {
            int s = csr_src[e];
            float cf = csr_coef[e];
            float2 v = *(const float2*)&h[(size_t)s * DIM + l * 2];
            ax += cf * v.x;
            ay += cf * v.y;
        }
        v2f o;
        o.x = ax; o.y = ay;
        __builtin_nontemporal_store(o, (v2f*)&m[(size_t)n * DIM + l * 2]);
    }
}

// ---------------- dense: h = leaky(BN(m @ W + cb)), optional fused score dots ----
__global__ __launch_bounds__(256) void gemm_bn_kernel(const float* __restrict__ m,
                                                      const float* __restrict__ W,
                                                      const float* __restrict__ cb,
                                                      const float* __restrict__ bg,
                                                      const float* __restrict__ bb,
                                                      const float* __restrict__ bm,
                                                      const float* __restrict__ bv,
                                                      float* __restrict__ h,
                                                      const float* __restrict__ wr,
                                                      const float* __restrict__ ws,
                                                      const float* __restrict__ pb,
                                                      float* __restrict__ tb,
                                                      float* __restrict__ sb,
                                                      int fuse_dots) {
    __shared__ float Wl[DIM * DIM];   // 64 KB
    __shared__ float Ml[32 * DIM];    // 16 KB
    int t = threadIdx.x;
    for (int i = t * 4; i < DIM * DIM; i += 1024)
        *(float4*)&Wl[i] = *(const float4*)&W[i];
    int cg = t & 31;   // column group (4 cols)
    int ns = t >> 5;   // node strip (4 nodes), 0..7
    float A[4], C[4];
#pragma unroll
    for (int c = 0; c < 4; ++c) {
        int d = cg * 4 + c;
        float inv = rsqrtf(bv[d] + 1e-5f);
        float a = bg[d] * inv;
        A[c] = a;
        C[c] = (cb[d] - bm[d]) * a + bb[d];
    }
    float4 wr4 = make_float4(0.f, 0.f, 0.f, 0.f), ws4 = wr4;
    float pb0 = 0.f;
    if (fuse_dots) {
        wr4 = ((const float4*)wr)[cg];
        ws4 = ((const float4*)ws)[cg];
        pb0 = pb[0];
    }
    __syncthreads();
    for (int tile = 0; tile < 4; ++tile) {
        int base = (blockIdx.x * 4 + tile) * 32;
        __syncthreads();
        for (int i = t * 4; i < 32 * DIM; i += 1024)
            *(float4*)&Ml[i] = *(const float4*)&m[base * DIM + i];
        __syncthreads();
        float acc[4][4] = {{0.f}};
        for (int k = 0; k < DIM; k += 4) {
            float4 a0 = *(float4*)&Ml[(ns * 4 + 0) * DIM + k];
            float4 a1 = *(float4*)&Ml[(ns * 4 + 1) * DIM + k];
            float4 a2 = *(float4*)&Ml[(ns * 4 + 2) * DIM + k];
            float4 a3 = *(float4*)&Ml[(ns * 4 + 3) * DIM + k];
            float4 b0 = *(float4*)&Wl[(k + 0) * DIM + cg * 4];
            float4 b1 = *(float4*)&Wl[(k + 1) * DIM + cg * 4];
            float4 b2 = *(float4*)&Wl[(k + 2) * DIM + cg * 4];
            float4 b3 = *(float4*)&Wl[(k + 3) * DIM + cg * 4];
            float av[4][4] = {{a0.x, a0.y, a0.z, a0.w},
                              {a1.x, a1.y, a1.z, a1.w},
                              {a2.x, a2.y, a2.z, a2.w},
                              {a3.x, a3.y, a3.z, a3.w}};
            float bvv[4][4] = {{b0.x, b0.y, b0.z, b0.w},
                               {b1.x, b1.y, b1.z, b1.w},
                               {b2.x, b2.y, b2.z, b2.w},
                               {b3.x, b3.y, b3.z, b3.w}};
#pragma unroll
            for (int u = 0; u < 4; ++u)
#pragma unroll
                for (int j = 0; j < 4; ++j)
#pragma unroll
                    for (int c = 0; c < 4; ++c)
                        acc[j][c] = fmaf(av[j][u], bvv[u][c], acc[j][c]);
        }
#pragma unroll
        for (int j = 0; j < 4; ++j) {
            int n = base + ns * 4 + j;
            float y0 = acc[j][0] * A[0] + C[0];
            float y1 = acc[j][1] * A[1] + C[1];
            float y2 = acc[j][2] * A[2] + C[2];
            float y3 = acc[j][3] * A[3] + C[3];
            float4 o;
            o.x = y0 > 0.f ? y0 : 0.01f * y0;
            o.y = y1 > 0.f ? y1 : 0.01f * y1;
            o.z = y2 > 0.f ? y2 : 0.01f * y2;
            o.w = y3 > 0.f ? y3 : 0.01f * y3;
            *(float4*)&h[n * DIM + cg * 4] = o;
            if (fuse_dots) {
                float tr = o.x * wr4.x + o.y * wr4.y + o.z * wr4.z + o.w * wr4.w;
                float ts = o.x * ws4.x + o.y * ws4.y + o.z * ws4.z + o.w * ws4.w;
#pragma unroll
                for (int off = 16; off; off >>= 1) {
                    tr += __shfl_xor(tr, off);
                    ts += __shfl_xor(ts, off);
                }
                if (cg == 0) {
                    tb[n] = tr;
                    sb[n] = ts + pb0;
                }
            }
        }
    }
}

__global__ void score_kernel(const int* __restrict__ rowptr, const int* __restrict__ csr_src,
                             const float* __restrict__ tb, float* __restrict__ sb) {
    int n = blockIdx.x * 256 + threadIdx.x;
    float s = sb[n];
    int e0 = rowptr[n], e1 = rowptr[n + 1];
    for (int e = e0; e < e1; ++e) s += tb[csr_src[e]];
    sb[n] = s;
}

// ---------------- per-graph top-K via 4-pass radix select (no serial chains) ----
__global__ __launch_bounds__(256) void select_kernel(const float* __restrict__ sb,
                                                     float* __restrict__ wsel) {
    __shared__ unsigned su[NPG];   // 32 KB
    __shared__ int hist[256];
    __shared__ int wsum[4];
    __shared__ unsigned pref_sh;
    __shared__ int kneed_sh;

    int b = blockIdx.x, t = threadIdx.x;
    int lane = t & 63, wv = t >> 6;
    const float* sc = &sb[b * NPG];
    for (int i = t; i < NPG; i += 256) {
        unsigned u = __float_as_uint(sc[i]);
        u = (u & 0x80000000u) ? ~u : (u | 0x80000000u);
        su[i] = u;
    }
    if (t == 0) { pref_sh = 0u; kneed_sh = KSEL; }
    __syncthreads();

    for (int p = 3; p >= 0; --p) {
        hist[t] = 0;
        __syncthreads();
        unsigned pref = pref_sh;
        int kneed = kneed_sh;
        int shift = p * 8;
        unsigned maskHi = (p == 3) ? 0u : (0xFFFFFFFFu << (shift + 8));
        for (int i = t; i < NPG; i += 256) {
            unsigned u = su[i];
            if ((u & maskHi) == (pref & maskHi))
                atomicAdd(&hist[(u >> shift) & 0xFFu], 1);
        }
        __syncthreads();
        int x = hist[t];
#pragma unroll
        for (int off = 1; off < 64; off <<= 1) {
            int y = __shfl_up(x, off);
            if (lane >= off) x += y;
        }
        if (lane == 63) wsum[wv] = x;
        __syncthreads();
        int add = 0, tot = 0;
#pragma unroll
        for (int j = 0; j < 4; ++j) {
            int v = wsum[j];
            tot += v;
            if (j < wv) add += v;
        }
        int psum = x + add;
        int cnt_gt = tot - psum;
        int myh = hist[t];
        __syncthreads();
        if (cnt_gt < kneed && cnt_gt + myh >= kneed) {
            pref_sh = (pref & maskHi) | ((unsigned)t << shift);
            kneed_sh = kneed - cnt_gt;
        }
        __syncthreads();
    }
    unsigned T = pref_sh;
    int need_eq = kneed_sh;

    int base = t * 32;
    int local = 0;
#pragma unroll
    for (int k = 0; k < 32; ++k) local += (su[base + k] == T) ? 1 : 0;
    int x = local;
#pragma unroll
    for (int off = 1; off < 64; off <<= 1) {
        int y = __shfl_up(x, off);
        if (lane >= off) x += y;
    }
    if (lane == 63) wsum[wv] = x;
    __syncthreads();
    int add = 0;
#pragma unroll
    for (int j = 0; j < 4; ++j)
        if (j < wv) add += wsum[j];
    int rank = (x - local) + add;
#pragma unroll
    for (int k = 0; k < 32; ++k) {
        unsigned u = su[base + k];
        bool take = (u > T);
        if (u == T) { take = (rank < need_eq); ++rank; }
        float w = 0.f;
        if (take) {
            float f = (u & 0x80000000u) ? __uint_as_float(u & 0x7FFFFFFFu)
                                        : __uint_as_float(~u);
            w = tanhf(f);
        }
        wsel[b * NPG + base + k] = w;
    }
}

// ---------------- weighted pool ----------------
__global__ __launch_bounds__(256) void pool_kernel(const float* __restrict__ wsel,
                                                   const float* __restrict__ h,
                                                   float* __restrict__ part) {
    int blk = blockIdx.x;
    int b = blk >> 5;
    int ch = blk & 31;
    int t = threadIdx.x;
    int nl = t >> 6;
    int l = t & 63;
    int n0 = b * NPG + ch * 256;
    float ax = 0.f, ay = 0.f;
    for (int i = nl; i < 256; i += 4) {
        int n = n0 + i;
        float w = wsel[n];
        if (w != 0.f) {
            float2 v = *(const float2*)&h[(size_t)n * DIM + l * 2];
            ax += w * v.x;
            ay += w * v.y;
        }
    }
    __shared__ float pp[4][DIM];
    pp[nl][l * 2] = ax;
    pp[nl][l * 2 + 1] = ay;
    __syncthreads();
    if (t < DIM) {
        float s = pp[0][t] + pp[1][t] + pp[2][t] + pp[3][t];
        part[((size_t)b * 32 + ch) * DIM + t] = s;
    }
}

__global__ void pool_reduce_kernel(const float* __restrict__ part,
                                   float* __restrict__ xg) {
    int b = blockIdx.x, d = threadIdx.x;
    float s = 0.f;
    for (int c = 0; c < 32; ++c) s += part[((size_t)b * 32 + c) * DIM + d];
    xg[b * DIM + d] = s;
}

// ---------------- final MLP ----------------
__global__ __launch_bounds__(1024) void mlp_kernel(const float* __restrict__ xg,
                                                   const float* __restrict__ r1w,
                                                   const float* __restrict__ r1b,
                                                   const float* __restrict__ r2w,
                                                   const float* __restrict__ r2b,
                                                   float* __restrict__ out) {
    __shared__ float h1[16 * 64];
    int t = threadIdx.x;
    {
        int b = t >> 6, j = t & 63;
        float acc = r1b[j];
        for (int k = 0; k < DIM; ++k) acc += xg[b * DIM + k] * r1w[k * 64 + j];
        h1[b * 64 + j] = acc > 0.f ? acc : 0.01f * acc;
    }
    __syncthreads();
    if (t < 64) {
        int b = t >> 2, o = t & 3;
        float acc = r2b[o];
        for (int k = 0; k < 64; ++k) acc += h1[b * 64 + k] * r2w[k * 4 + o];
        out[b * 4 + o] = acc;
    }
}

extern "C" void kernel_launch(void* const* d_in, const int* in_sizes, int n_in,
                              void* d_out, int out_size, void* d_ws, size_t ws_size,
                              hipStream_t stream) {
    const float* x       = (const float*)d_in[0];
    const int*   ei      = (const int*)d_in[2];
    const float* node_w  = (const float*)d_in[3];
    const float* node_b  = (const float*)d_in[4];
    const float* conv_w  = (const float*)d_in[7];
    const float* conv_b  = (const float*)d_in[8];
    const float* bn_g    = (const float*)d_in[9];
    const float* bn_b    = (const float*)d_in[10];
    const float* bn_m    = (const float*)d_in[11];
    const float* bn_v    = (const float*)d_in[12];
    const float* pool_wr = (const float*)d_in[13];
    const float* pool_ws = (const float*)d_in[14];
    const float* pool_b  = (const float*)d_in[15];
    const float* r1_w    = (const float*)d_in[16];
    const float* r1_b    = (const float*)d_in[17];
    const float* r2_w    = (const float*)d_in[18];
    const float* r2_b    = (const float*)d_in[19];
    float* out = (float*)d_out;

    char* ws = (char*)d_ws;
    size_t off = 0;
    auto alloc = [&](size_t bytes) {
        void* p = ws + off;
        off = (off + bytes + 255) & ~(size_t)255;
        return p;
    };
    float* h       = (float*)alloc((size_t)N_NODES * DIM * 4);
    float* mbuf    = (float*)alloc((size_t)N_NODES * DIM * 4);
    int*   deg     = (int*)alloc((size_t)N_NODES * 4);
    int*   rowptr  = (int*)alloc((size_t)(N_NODES + 1) * 4);
    int*   cursor  = (int*)alloc((size_t)N_NODES * 4);
    float* dis     = (float*)alloc((size_t)N_NODES * 4);
    int*   csr_src = (int*)alloc((size_t)E_EDGES * 4);
    float* csr_cf  = (float*)alloc((size_t)E_EDGES * 4);
    float* tb      = (float*)alloc((size_t)N_NODES * 4);
    float* sb      = (float*)alloc((size_t)N_NODES * 4);
    float* wsel    = (float*)alloc((size_t)N_NODES * 4);
    float* part    = (float*)alloc((size_t)NGRAPH * 32 * DIM * 4);
    float* xg      = (float*)alloc((size_t)NGRAPH * DIM * 4);

    hipMemsetAsync(deg, 0, (size_t)N_NODES * 4, stream);
    count_deg_kernel<<<E_EDGES / 256, 256, 0, stream>>>(ei, deg);
    scan_kernel<<<1, 1024, 0, stream>>>(deg, rowptr, cursor, dis);
    fill_csr_kernel<<<E_EDGES / 256, 256, 0, stream>>>(ei, cursor, dis, csr_src, csr_cf);
    embed_kernel<<<N_NODES / 32, 256, 0, stream>>>(x, node_w, node_b, h);

    for (int layer = 0; layer < 3; ++layer) {
        agg_kernel<<<8192, 256, 0, stream>>>(h, rowptr, csr_src, csr_cf, dis, mbuf);
        gemm_bn_kernel<<<N_NODES / 128, 256, 0, stream>>>(
            mbuf, conv_w + (size_t)layer * DIM * DIM, conv_b + layer * DIM,
            bn_g + layer * DIM, bn_b + layer * DIM, bn_m + layer * DIM,
            bn_v + layer * DIM, h,
            pool_wr, pool_ws, pool_b, tb, sb, (layer == 2) ? 1 : 0);
    }

    score_kernel<<<N_NODES / 256, 256, 0, stream>>>(rowptr, csr_src, tb, sb);
    select_kernel<<<NGRAPH, 256, 0, stream>>>(sb, wsel);
    pool_kernel<<<NGRAPH * 32, 256, 0, stream>>>(wsel, h, part);
    pool_reduce_kernel<<<NGRAPH, DIM, 0, stream>>>(part, xg);
    mlp_kernel<<<1, 1024, 0, stream>>>(xg, r1_w, r1_b, r2_w, r2_b, out);
}

// Round 5
// 586.624 us; speedup vs baseline: 2.1081x; 1.1378x over previous
//
#include <hip/hip_runtime.h>

#define N_NODES 131072
#define E_EDGES 524288
#define NGRAPH  16
#define NPG     8192
#define DIM     128
#define KSEL    4096
#define SCAN_BLOCKS 128   // N_NODES / 1024

typedef float v2f __attribute__((ext_vector_type(2)));

// ---------------- CSR build ----------------
__global__ void count_deg_kernel(const int* __restrict__ ei, int* __restrict__ deg) {
    int e = blockIdx.x * 256 + threadIdx.x;
    atomicAdd(&deg[ei[E_EDGES + e]], 1);
}

// phase 1: per-block (1024 elems) sums
__global__ __launch_bounds__(256) void scan_partial_kernel(const int* __restrict__ deg,
                                                           int* __restrict__ bsum) {
    __shared__ int wsh[4];
    int b = blockIdx.x, t = threadIdx.x;
    int4 v = ((const int4*)&deg[b * 1024])[t];
    int s = v.x + v.y + v.z + v.w;
#pragma unroll
    for (int off = 32; off; off >>= 1) s += __shfl_xor(s, off);
    if ((t & 63) == 0) wsh[t >> 6] = s;
    __syncthreads();
    if (t == 0) bsum[b] = wsh[0] + wsh[1] + wsh[2] + wsh[3];
}

// phase 2: exclusive scan of the 128 block sums (1 block, 128 threads)
__global__ __launch_bounds__(128) void scan_bsum_kernel(const int* __restrict__ bsum,
                                                        int* __restrict__ boff,
                                                        int* __restrict__ rowptr) {
    __shared__ int w0;
    int t = threadIdx.x;
    int lane = t & 63;
    int v = bsum[t];
    int x = v;
#pragma unroll
    for (int off = 1; off < 64; off <<= 1) {
        int y = __shfl_up(x, off);
        if (lane >= off) x += y;
    }
    if (t == 63) w0 = x;
    __syncthreads();
    int incl = x + ((t >= 64) ? w0 : 0);
    boff[t] = incl - v;
    if (t == 127) rowptr[N_NODES] = incl;
}

// phase 3: local prefix + global offset -> rowptr, cursor, dis
__global__ __launch_bounds__(256) void scan_final_kernel(const int* __restrict__ deg,
                                                         const int* __restrict__ boff,
                                                         int* __restrict__ rowptr,
                                                         int* __restrict__ cursor,
                                                         float* __restrict__ dis) {
    __shared__ int wsum[4];
    int b = blockIdx.x, t = threadIdx.x;
    int lane = t & 63, wv = t >> 6;
    int4 v = ((const int4*)&deg[b * 1024])[t];
    int s = v.x + v.y + v.z + v.w;
    int x = s;
#pragma unroll
    for (int off = 1; off < 64; off <<= 1) {
        int y = __shfl_up(x, off);
        if (lane >= off) x += y;
    }
    if (lane == 63) wsum[wv] = x;
    __syncthreads();
    int add = boff[b];
#pragma unroll
    for (int j = 0; j < 4; ++j)
        if (j < wv) add += wsum[j];
    int excl = add + (x - s);
    int base = b * 1024 + t * 4;
    int4 rp;
    rp.x = excl;
    rp.y = excl + v.x;
    rp.z = rp.y + v.y;
    rp.w = rp.z + v.z;
    *(int4*)&rowptr[base] = rp;
    *(int4*)&cursor[base] = rp;
    float4 dv;
    dv.x = rsqrtf((float)v.x + 1.0f);
    dv.y = rsqrtf((float)v.y + 1.0f);
    dv.z = rsqrtf((float)v.z + 1.0f);
    dv.w = rsqrtf((float)v.w + 1.0f);
    *(float4*)&dis[base] = dv;
}

__global__ void fill_csr_kernel(const int* __restrict__ ei, int* __restrict__ cursor,
                                const float* __restrict__ dis, int* __restrict__ csr_src,
                                float* __restrict__ csr_coef) {
    int e = blockIdx.x * 256 + threadIdx.x;
    int s = ei[e];
    int d = ei[E_EDGES + e];
    int p = atomicAdd(&cursor[d], 1);
    csr_src[p] = s;
    csr_coef[p] = dis[s] * dis[d];
}

// ---------------- node embedding: h = x @ node_w + node_b ----------------
__global__ __launch_bounds__(256) void embed_kernel(const float* __restrict__ x,
                                                    const float* __restrict__ nw,
                                                    const float* __restrict__ nb,
                                                    float* __restrict__ h) {
    __shared__ float Wl[16 * DIM];
    int t = threadIdx.x;
    for (int i = t * 4; i < 16 * DIM; i += 1024)
        *(float4*)&Wl[i] = *(const float4*)&nw[i];
    __syncthreads();
    int d = t & 127, sub = t >> 7;
    float bias = nb[d];
    int base = blockIdx.x * 32;
    for (int k = 0; k < 16; ++k) {
        int n = base + k * 2 + sub;
        const float* xr = &x[n * 16];
        float acc = bias;
#pragma unroll
        for (int f = 0; f < 16; ++f) acc += xr[f] * Wl[f * DIM + d];
        h[n * DIM + d] = acc;
    }
}

// ---------------- sparse propagate: m = sum coef*h[src] + dis^2 * h ----------------
__global__ __launch_bounds__(256) void agg_kernel(const float* __restrict__ h,
                                                  const int* __restrict__ rowptr,
                                                  const int* __restrict__ csr_src,
                                                  const float* __restrict__ csr_coef,
                                                  const float* __restrict__ dis,
                                                  float* __restrict__ m) {
    int bb = blockIdx.x;
    int xslot = bb & 7;
    int c = bb >> 3;                 // 0..1023
    int g = xslot + ((c >= 512) ? 8 : 0);
    int chunk = c & 511;             // 0..511
    int t = threadIdx.x;
    int nl = t >> 6, l = t & 63;
    int nbase = g * NPG + chunk * 16;
#pragma unroll
    for (int it = 0; it < 4; ++it) {
        int n = nbase + it * 4 + nl;
        float dn = dis[n];
        float2 hv = *(const float2*)&h[(size_t)n * DIM + l * 2];
        float ax = dn * dn * hv.x;
        float ay = dn * dn * hv.y;
        int e0 = rowptr[n], e1 = rowptr[n + 1];
        for (int e = e0; e < e1; ++e) {
            int s = csr_src[e];
            float cf = csr_coef[e];
            float2 v = *(const float2*)&h[(size_t)s * DIM + l * 2];
            ax += cf * v.x;
            ay += cf * v.y;
        }
        v2f o;
        o.x = ax; o.y = ay;
        __builtin_nontemporal_store(o, (v2f*)&m[(size_t)n * DIM + l * 2]);
    }
}

// ---------------- dense: h = leaky(BN(m @ W + cb)), optional fused score dots ----
// 256 nodes/block (8 tiles of 32); T14 async-stage: next tile's global loads
// issued before compute, ds_write after the post-compute barrier.
__global__ __launch_bounds__(256) void gemm_bn_kernel(const float* __restrict__ m,
                                                      const float* __restrict__ W,
                                                      const float* __restrict__ cb,
                                                      const float* __restrict__ bg,
                                                      const float* __restrict__ bb,
                                                      const float* __restrict__ bm,
                                                      const float* __restrict__ bv,
                                                      float* __restrict__ h,
                                                      const float* __restrict__ wr,
                                                      const float* __restrict__ ws,
                                                      const float* __restrict__ pb,
                                                      float* __restrict__ tb,
                                                      float* __restrict__ sb,
                                                      int fuse_dots) {
    __shared__ float Wl[DIM * DIM];   // 64 KB
    __shared__ float Ml[32 * DIM];    // 16 KB  -> 80 KB total, 2 blocks/CU
    int t = threadIdx.x;
    int cg = t & 31;   // column group (4 cols)
    int ns = t >> 5;   // node strip (4 nodes), 0..7
    int blockbase = blockIdx.x * 256;

    // prefetch tile 0 into registers
    float4 pre[4];
    {
        const float4* g = (const float4*)&m[(size_t)blockbase * DIM];
#pragma unroll
        for (int j = 0; j < 4; ++j) pre[j] = g[t + j * 256];
    }
    // stage W
    for (int i = t; i < DIM * DIM / 4; i += 256)
        ((float4*)Wl)[i] = ((const float4*)W)[i];

    float A[4], C[4];
#pragma unroll
    for (int c = 0; c < 4; ++c) {
        int d = cg * 4 + c;
        float inv = rsqrtf(bv[d] + 1e-5f);
        float a = bg[d] * inv;
        A[c] = a;
        C[c] = (cb[d] - bm[d]) * a + bb[d];
    }
    float4 wr4 = make_float4(0.f, 0.f, 0.f, 0.f), ws4 = wr4;
    float pb0 = 0.f;
    if (fuse_dots) {
        wr4 = ((const float4*)wr)[cg];
        ws4 = ((const float4*)ws)[cg];
        pb0 = pb[0];
    }
    // write tile 0 to LDS
#pragma unroll
    for (int j = 0; j < 4; ++j) ((float4*)Ml)[t + j * 256] = pre[j];
    __syncthreads();

    for (int tile = 0; tile < 8; ++tile) {
        int base = blockbase + tile * 32;
        if (tile < 7) {
            const float4* g = (const float4*)&m[(size_t)(base + 32) * DIM];
#pragma unroll
            for (int j = 0; j < 4; ++j) pre[j] = g[t + j * 256];
        }
        float acc[4][4] = {{0.f}};
        for (int k = 0; k < DIM; k += 4) {
            float4 a0 = *(float4*)&Ml[(ns * 4 + 0) * DIM + k];
            float4 a1 = *(float4*)&Ml[(ns * 4 + 1) * DIM + k];
            float4 a2 = *(float4*)&Ml[(ns * 4 + 2) * DIM + k];
            float4 a3 = *(float4*)&Ml[(ns * 4 + 3) * DIM + k];
            float4 b0 = *(float4*)&Wl[(k + 0) * DIM + cg * 4];
            float4 b1 = *(float4*)&Wl[(k + 1) * DIM + cg * 4];
            float4 b2 = *(float4*)&Wl[(k + 2) * DIM + cg * 4];
            float4 b3 = *(float4*)&Wl[(k + 3) * DIM + cg * 4];
            float av[4][4] = {{a0.x, a0.y, a0.z, a0.w},
                              {a1.x, a1.y, a1.z, a1.w},
                              {a2.x, a2.y, a2.z, a2.w},
                              {a3.x, a3.y, a3.z, a3.w}};
            float bvv[4][4] = {{b0.x, b0.y, b0.z, b0.w},
                               {b1.x, b1.y, b1.z, b1.w},
                               {b2.x, b2.y, b2.z, b2.w},
                               {b3.x, b3.y, b3.z, b3.w}};
#pragma unroll
            for (int u = 0; u < 4; ++u)
#pragma unroll
                for (int j = 0; j < 4; ++j)
#pragma unroll
                    for (int c = 0; c < 4; ++c)
                        acc[j][c] = fmaf(av[j][u], bvv[u][c], acc[j][c]);
        }
#pragma unroll
        for (int j = 0; j < 4; ++j) {
            int n = base + ns * 4 + j;
            float y0 = acc[j][0] * A[0] + C[0];
            float y1 = acc[j][1] * A[1] + C[1];
            float y2 = acc[j][2] * A[2] + C[2];
            float y3 = acc[j][3] * A[3] + C[3];
            float4 o;
            o.x = y0 > 0.f ? y0 : 0.01f * y0;
            o.y = y1 > 0.f ? y1 : 0.01f * y1;
            o.z = y2 > 0.f ? y2 : 0.01f * y2;
            o.w = y3 > 0.f ? y3 : 0.01f * y3;
            *(float4*)&h[n * DIM + cg * 4] = o;
            if (fuse_dots) {
                float tr = o.x * wr4.x + o.y * wr4.y + o.z * wr4.z + o.w * wr4.w;
                float ts = o.x * ws4.x + o.y * ws4.y + o.z * ws4.z + o.w * ws4.w;
#pragma unroll
                for (int off = 16; off; off >>= 1) {
                    tr += __shfl_xor(tr, off);
                    ts += __shfl_xor(ts, off);
                }
                if (cg == 0) {
                    tb[n] = tr;
                    sb[n] = ts + pb0;
                }
            }
        }
        __syncthreads();
        if (tile < 7) {
#pragma unroll
            for (int j = 0; j < 4; ++j) ((float4*)Ml)[t + j * 256] = pre[j];
            __syncthreads();
        }
    }
}

__global__ void score_kernel(const int* __restrict__ rowptr, const int* __restrict__ csr_src,
                             const float* __restrict__ tb, float* __restrict__ sb) {
    int n = blockIdx.x * 256 + threadIdx.x;
    float s = sb[n];
    int e0 = rowptr[n], e1 = rowptr[n + 1];
    for (int e = e0; e < e1; ++e) s += tb[csr_src[e]];
    sb[n] = s;
}

// ---------------- per-graph top-K via 4-pass radix select ----------------
__global__ __launch_bounds__(256) void select_kernel(const float* __restrict__ sb,
                                                     float* __restrict__ wsel) {
    __shared__ unsigned su[NPG];   // 32 KB
    __shared__ int hist[256];
    __shared__ int wsum[4];
    __shared__ unsigned pref_sh;
    __shared__ int kneed_sh;

    int b = blockIdx.x, t = threadIdx.x;
    int lane = t & 63, wv = t >> 6;
    const float* sc = &sb[b * NPG];
    for (int i = t; i < NPG; i += 256) {
        unsigned u = __float_as_uint(sc[i]);
        u = (u & 0x80000000u) ? ~u : (u | 0x80000000u);
        su[i] = u;
    }
    if (t == 0) { pref_sh = 0u; kneed_sh = KSEL; }
    __syncthreads();

    for (int p = 3; p >= 0; --p) {
        hist[t] = 0;
        __syncthreads();
        unsigned pref = pref_sh;
        int kneed = kneed_sh;
        int shift = p * 8;
        unsigned maskHi = (p == 3) ? 0u : (0xFFFFFFFFu << (shift + 8));
        for (int i = t; i < NPG; i += 256) {
            unsigned u = su[i];
            if ((u & maskHi) == (pref & maskHi))
                atomicAdd(&hist[(u >> shift) & 0xFFu], 1);
        }
        __syncthreads();
        int x = hist[t];
#pragma unroll
        for (int off = 1; off < 64; off <<= 1) {
            int y = __shfl_up(x, off);
            if (lane >= off) x += y;
        }
        if (lane == 63) wsum[wv] = x;
        __syncthreads();
        int add = 0, tot = 0;
#pragma unroll
        for (int j = 0; j < 4; ++j) {
            int v = wsum[j];
            tot += v;
            if (j < wv) add += v;
        }
        int psum = x + add;
        int cnt_gt = tot - psum;
        int myh = hist[t];
        __syncthreads();
        if (cnt_gt < kneed && cnt_gt + myh >= kneed) {
            pref_sh = (pref & maskHi) | ((unsigned)t << shift);
            kneed_sh = kneed - cnt_gt;
        }
        __syncthreads();
    }
    unsigned T = pref_sh;
    int need_eq = kneed_sh;

    int base = t * 32;
    int local = 0;
#pragma unroll
    for (int k = 0; k < 32; ++k) local += (su[base + k] == T) ? 1 : 0;
    int x = local;
#pragma unroll
    for (int off = 1; off < 64; off <<= 1) {
        int y = __shfl_up(x, off);
        if (lane >= off) x += y;
    }
    if (lane == 63) wsum[wv] = x;
    __syncthreads();
    int add = 0;
#pragma unroll
    for (int j = 0; j < 4; ++j)
        if (j < wv) add += wsum[j];
    int rank = (x - local) + add;
#pragma unroll
    for (int k = 0; k < 32; ++k) {
        unsigned u = su[base + k];
        bool take = (u > T);
        if (u == T) { take = (rank < need_eq); ++rank; }
        float w = 0.f;
        if (take) {
            float f = (u & 0x80000000u) ? __uint_as_float(u & 0x7FFFFFFFu)
                                        : __uint_as_float(~u);
            w = tanhf(f);
        }
        wsel[b * NPG + base + k] = w;
    }
}

// ---------------- weighted pool ----------------
__global__ __launch_bounds__(256) void pool_kernel(const float* __restrict__ wsel,
                                                   const float* __restrict__ h,
                                                   float* __restrict__ part) {
    int blk = blockIdx.x;
    int b = blk >> 5;
    int ch = blk & 31;
    int t = threadIdx.x;
    int nl = t >> 6;
    int l = t & 63;
    int n0 = b * NPG + ch * 256;
    float ax = 0.f, ay = 0.f;
    for (int i = nl; i < 256; i += 4) {
        int n = n0 + i;
        float w = wsel[n];
        if (w != 0.f) {
            float2 v = *(const float2*)&h[(size_t)n * DIM + l * 2];
            ax += w * v.x;
            ay += w * v.y;
        }
    }
    __shared__ float pp[4][DIM];
    pp[nl][l * 2] = ax;
    pp[nl][l * 2 + 1] = ay;
    __syncthreads();
    if (t < DIM) {
        float s = pp[0][t] + pp[1][t] + pp[2][t] + pp[3][t];
        part[((size_t)b * 32 + ch) * DIM + t] = s;
    }
}

__global__ void pool_reduce_kernel(const float* __restrict__ part,
                                   float* __restrict__ xg) {
    int b = blockIdx.x, d = threadIdx.x;
    float s = 0.f;
    for (int c = 0; c < 32; ++c) s += part[((size_t)b * 32 + c) * DIM + d];
    xg[b * DIM + d] = s;
}

// ---------------- final MLP ----------------
__global__ __launch_bounds__(1024) void mlp_kernel(const float* __restrict__ xg,
                                                   const float* __restrict__ r1w,
                                                   const float* __restrict__ r1b,
                                                   const float* __restrict__ r2w,
                                                   const float* __restrict__ r2b,
                                                   float* __restrict__ out) {
    __shared__ float h1[16 * 64];
    int t = threadIdx.x;
    {
        int b = t >> 6, j = t & 63;
        float acc = r1b[j];
        for (int k = 0; k < DIM; ++k) acc += xg[b * DIM + k] * r1w[k * 64 + j];
        h1[b * 64 + j] = acc > 0.f ? acc : 0.01f * acc;
    }
    __syncthreads();
    if (t < 64) {
        int b = t >> 2, o = t & 3;
        float acc = r2b[o];
        for (int k = 0; k < 64; ++k) acc += h1[b * 64 + k] * r2w[k * 4 + o];
        out[b * 4 + o] = acc;
    }
}

extern "C" void kernel_launch(void* const* d_in, const int* in_sizes, int n_in,
                              void* d_out, int out_size, void* d_ws, size_t ws_size,
                              hipStream_t stream) {
    const float* x       = (const float*)d_in[0];
    const int*   ei      = (const int*)d_in[2];
    const float* node_w  = (const float*)d_in[3];
    const float* node_b  = (const float*)d_in[4];
    const float* conv_w  = (const float*)d_in[7];
    const float* conv_b  = (const float*)d_in[8];
    const float* bn_g    = (const float*)d_in[9];
    const float* bn_b    = (const float*)d_in[10];
    const float* bn_m    = (const float*)d_in[11];
    const float* bn_v    = (const float*)d_in[12];
    const float* pool_wr = (const float*)d_in[13];
    const float* pool_ws = (const float*)d_in[14];
    const float* pool_b  = (const float*)d_in[15];
    const float* r1_w    = (const float*)d_in[16];
    const float* r1_b    = (const float*)d_in[17];
    const float* r2_w    = (const float*)d_in[18];
    const float* r2_b    = (const float*)d_in[19];
    float* out = (float*)d_out;

    char* ws = (char*)d_ws;
    size_t off = 0;
    auto alloc = [&](size_t bytes) {
        void* p = ws + off;
        off = (off + bytes + 255) & ~(size_t)255;
        return p;
    };
    float* h       = (float*)alloc((size_t)N_NODES * DIM * 4);
    float* mbuf    = (float*)alloc((size_t)N_NODES * DIM * 4);
    int*   deg     = (int*)alloc((size_t)N_NODES * 4);
    int*   rowptr  = (int*)alloc((size_t)(N_NODES + 1) * 4);
    int*   cursor  = (int*)alloc((size_t)N_NODES * 4);
    float* dis     = (float*)alloc((size_t)N_NODES * 4);
    int*   csr_src = (int*)alloc((size_t)E_EDGES * 4);
    float* csr_cf  = (float*)alloc((size_t)E_EDGES * 4);
    float* tb      = (float*)alloc((size_t)N_NODES * 4);
    float* sb      = (float*)alloc((size_t)N_NODES * 4);
    float* wsel    = (float*)alloc((size_t)N_NODES * 4);
    float* part    = (float*)alloc((size_t)NGRAPH * 32 * DIM * 4);
    float* xg      = (float*)alloc((size_t)NGRAPH * DIM * 4);
    int*   bsum    = (int*)alloc((size_t)SCAN_BLOCKS * 4);
    int*   boff    = (int*)alloc((size_t)SCAN_BLOCKS * 4);

    hipMemsetAsync(deg, 0, (size_t)N_NODES * 4, stream);
    count_deg_kernel<<<E_EDGES / 256, 256, 0, stream>>>(ei, deg);
    scan_partial_kernel<<<SCAN_BLOCKS, 256, 0, stream>>>(deg, bsum);
    scan_bsum_kernel<<<1, 128, 0, stream>>>(bsum, boff, rowptr);
    scan_final_kernel<<<SCAN_BLOCKS, 256, 0, stream>>>(deg, boff, rowptr, cursor, dis);
    fill_csr_kernel<<<E_EDGES / 256, 256, 0, stream>>>(ei, cursor, dis, csr_src, csr_cf);
    embed_kernel<<<N_NODES / 32, 256, 0, stream>>>(x, node_w, node_b, h);

    for (int layer = 0; layer < 3; ++layer) {
        agg_kernel<<<8192, 256, 0, stream>>>(h, rowptr, csr_src, csr_cf, dis, mbuf);
        gemm_bn_kernel<<<N_NODES / 256, 256, 0, stream>>>(
            mbuf, conv_w + (size_t)layer * DIM * DIM, conv_b + layer * DIM,
            bn_g + layer * DIM, bn_b + layer * DIM, bn_m + layer * DIM,
            bn_v + layer * DIM, h,
            pool_wr, pool_ws, pool_b, tb, sb, (layer == 2) ? 1 : 0);
    }

    score_kernel<<<N_NODES / 256, 256, 0, stream>>>(rowptr, csr_src, tb, sb);
    select_kernel<<<NGRAPH, 256, 0, stream>>>(sb, wsel);
    pool_kernel<<<NGRAPH * 32, 256, 0, stream>>>(wsel, h, part);
    pool_reduce_kernel<<<NGRAPH, DIM, 0, stream>>>(part, xg);
    mlp_kernel<<<1, 1024, 0, stream>>>(xg, r1_w, r1_b, r2_w, r2_b, out);
}